// Round 15
// baseline (194.289 us; speedup 1.0000x reference)
//
#include <hip/hip_runtime.h>
#include <hip/hip_bf16.h>

typedef float f32x4 __attribute__((ext_vector_type(4)));
typedef float f32x16 __attribute__((ext_vector_type(16)));
typedef short s16x8 __attribute__((ext_vector_type(8)));
typedef uint  u32x4 __attribute__((ext_vector_type(4)));

#define MFMA_BF16(a, b, c) __builtin_amdgcn_mfma_f32_16x16x32_bf16((a), (b), (c), 0, 0, 0)
#define MFMA32(a, b, c)    __builtin_amdgcn_mfma_f32_32x32x16_bf16((a), (b), (c), 0, 0, 0)

// ---------- helpers ----------
__device__ __forceinline__ ushort f2bf(float f) {
  uint u = __builtin_bit_cast(uint, f);
  u += 0x7FFFu + ((u >> 16) & 1u);
  return (ushort)(u >> 16);
}
__device__ __forceinline__ uint pack2bf(float a, float b) {
  return (uint)f2bf(a) | ((uint)f2bf(b) << 16);
}
// exp(s - 30) = exp2(fma(s, log2e, -30*log2e))
__device__ __forceinline__ float pexp(float s) {
  float t = fmaf(s, 1.4426950408889634f, -43.2808512266689f);
  float r;
  asm("v_exp_f32 %0, %1" : "=v"(r) : "v"(t));
  return r;
}
__device__ __forceinline__ uint cvtpk(float lo, float hi) {
  uint r;
  asm("v_cvt_pk_bf16_f32 %0, %1, %2" : "=v"(r) : "v"(lo), "v"(hi));
  return r;
}
__device__ __forceinline__ void plswap(uint& a, uint& b) {
  asm("v_permlane32_swap_b32 %0, %1" : "+v"(a), "+v"(b));
}
__device__ __forceinline__ void gld16(const void* g, void* l) {
  __builtin_amdgcn_global_load_lds(
      (const __attribute__((address_space(1))) unsigned int*)g,
      (__attribute__((address_space(3))) unsigned int*)l, 16, 0, 0);
}

// ---------- ws layout (bytes) ----------
// dmat FRAGMENT-MAJOR: elem (b,c,i) at ((((b*256 + (i>>4))*16 + (c>>5))*64
//                                        + ((i>>3)&1)*32 + (c&31))*8 + (i&7)
// bT rows unit-swizzled: 16B unit u at row i stored at u^(i&7)
// E: frag-major exp(S-30) bf16: frag f = (((b*64 + IC)*128 + J)*4 + ch),
//    elem (f*64 + lane)*8 + e
#define WS_XT    0UL
#define WS_D     16777216UL
#define WS_BT    33554432UL
#define WS_CT    35651584UL
#define WS_WCAT  37748736UL
#define WS_BCAT  38404096UL
#define WS_E     41943040UL
#define WS_E_NEED (WS_E + 134217728UL)

// ---------- kernel 1: pack weights to bf16 [640][512] + bias concat ----------
__global__ void k_prep_w(const float* __restrict__ Wb, const float* __restrict__ bb,
                         const float* __restrict__ Wc, const float* __restrict__ bc,
                         const float* __restrict__ Wd, const float* __restrict__ bd,
                         ushort* __restrict__ Wcat, float* __restrict__ bcat) {
  int idx = blockIdx.x * 256 + threadIdx.x;
  if (idx < 640 * 512) {
    int m = idx >> 9, k = idx & 511;
    float v = (m < 64) ? Wb[m * 512 + k] : (m < 128) ? Wc[(m - 64) * 512 + k] : Wd[(m - 128) * 512 + k];
    Wcat[idx] = f2bf(v);
  }
  if (idx < 640) {
    bcat[idx] = (idx < 64) ? bb[idx] : (idx < 128) ? bc[idx - 64] : bd[idx - 128];
  }
}

// ---------- kernel 2: transpose x [B][512][4096] f32 -> xT [B][4096][512] bf16 ----------
__global__ __launch_bounds__(256) void k_prep_xt(const float* __restrict__ x, ushort* __restrict__ xT) {
  __shared__ float tile[64][65];
  int bx = blockIdx.x;
  int b = bx >> 9;                  // 8*64 = 512 tiles per batch
  int c0 = ((bx >> 6) & 7) * 64;
  int n0 = (bx & 63) * 64;
  int t = threadIdx.x;
  const float* xb = x + (size_t)b * 512 * 4096;
#pragma unroll
  for (int p = 0; p < 4; ++p) {
    int cl = (t >> 4) + 16 * p;
    int nf = (t & 15) * 4;
    float4 v = *reinterpret_cast<const float4*>(xb + (size_t)(c0 + cl) * 4096 + n0 + nf);
    tile[cl][nf + 0] = v.x; tile[cl][nf + 1] = v.y; tile[cl][nf + 2] = v.z; tile[cl][nf + 3] = v.w;
  }
  __syncthreads();
  ushort* dst = xT + (size_t)b * 4096 * 512;
#pragma unroll
  for (int q = 0; q < 2; ++q) {
    int ch = t + 256 * q;
    int nl = ch >> 3;
    int cf = (ch & 7) * 8;
    uint4 o;
    o.x = pack2bf(tile[cf + 0][nl], tile[cf + 1][nl]);
    o.y = pack2bf(tile[cf + 2][nl], tile[cf + 3][nl]);
    o.z = pack2bf(tile[cf + 4][nl], tile[cf + 5][nl]);
    o.w = pack2bf(tile[cf + 6][nl], tile[cf + 7][nl]);
    *reinterpret_cast<uint4*>(dst + (size_t)(n0 + nl) * 512 + c0 + cf) = o;
  }
}

// ---------- kernel 3: projection GEMM [640 x 4096, K=512] per batch ----------
__global__ __launch_bounds__(256) void k_proj(const ushort* __restrict__ Wcat, const float* __restrict__ bcat,
                                              const ushort* __restrict__ xT, ushort* __restrict__ bT,
                                              ushort* __restrict__ cT, ushort* __restrict__ dmat) {
  int bx = blockIdx.x;
  int b = bx / 160;
  int r = bx % 160;
  int m0 = (r >> 5) * 128;    // 5 m-tiles
  int n0 = (r & 31) * 128;    // 32 n-tiles
  int t = threadIdx.x, l = t & 63, w = t >> 6;
  int wm = w >> 1, wn = w & 1, g = l >> 4, l15 = l & 15;
  const ushort* xb = xT + (size_t)b * 4096 * 512;
  f32x4 acc[4][4] = {};
  s16x8 bfn[4];
#pragma unroll
  for (int nt = 0; nt < 4; ++nt)
    bfn[nt] = *reinterpret_cast<const s16x8*>(xb + (size_t)(n0 + 64 * wn + 16 * nt + l15) * 512 + 8 * g);
  for (int k0 = 0; k0 < 512; k0 += 32) {
    s16x8 a[4], bf[4];
#pragma unroll
    for (int nt = 0; nt < 4; ++nt) bf[nt] = bfn[nt];
#pragma unroll
    for (int mt = 0; mt < 4; ++mt)
      a[mt] = *reinterpret_cast<const s16x8*>(Wcat + (size_t)(m0 + 64 * wm + 16 * mt + l15) * 512 + k0 + 8 * g);
    if (k0 + 32 < 512) {
#pragma unroll
      for (int nt = 0; nt < 4; ++nt)
        bfn[nt] = *reinterpret_cast<const s16x8*>(xb + (size_t)(n0 + 64 * wn + 16 * nt + l15) * 512 + k0 + 32 + 8 * g);
    }
    __builtin_amdgcn_sched_barrier(0);
#pragma unroll
    for (int mt = 0; mt < 4; ++mt)
#pragma unroll
      for (int nt = 0; nt < 4; ++nt)
        acc[mt][nt] = MFMA_BF16(a[mt], bf[nt], acc[mt][nt]);
  }
#pragma unroll
  for (int mt = 0; mt < 4; ++mt) {
    int mbase = m0 + 64 * wm + 16 * mt + 4 * g;
#pragma unroll
    for (int nt = 0; nt < 4; ++nt) {
      int n = n0 + 64 * wn + 16 * nt + l15;
      float vv[4];
      vv[0] = acc[mt][nt][0] + bcat[mbase + 0];
      vv[1] = acc[mt][nt][1] + bcat[mbase + 1];
      vv[2] = acc[mt][nt][2] + bcat[mbase + 2];
      vv[3] = acc[mt][nt][3] + bcat[mbase + 3];
      if (mbase < 64) {
        // bT swizzled: unit u=mbase>>3 stored at u^(n&7); mbase&4 selects 8B half
        uint2 u2; u2.x = pack2bf(vv[0], vv[1]); u2.y = pack2bf(vv[2], vv[3]);
        size_t off = ((size_t)b * 4096 + n) * 64 + (size_t)((((mbase >> 3) ^ (n & 7)) << 3) + (mbase & 4));
        *reinterpret_cast<uint2*>(bT + off) = u2;
      } else if (mbase < 128) {
        uint2 u2; u2.x = pack2bf(vv[0], vv[1]); u2.y = pack2bf(vv[2], vv[3]);
        *reinterpret_cast<uint2*>(cT + ((size_t)b * 4096 + n) * 64 + (mbase - 64)) = u2;
      } else {
        // d fragment-major: (b, c, i=n)
        int cc = mbase - 128;
        size_t fb = (((size_t)b * 256 + (n >> 4)) * 16) * 512;  // *64 lanes *8 elems
#pragma unroll
        for (int rr = 0; rr < 4; ++rr) {
          int c = cc + rr;
          size_t idx = fb + (size_t)(c >> 5) * 512 + (size_t)(((n >> 3) & 1) * 32 + (c & 31)) * 8 + (n & 7);
          dmat[idx] = f2bf(vv[rr]);
        }
      }
    }
  }
}

// ---------- kernel 4e: stats + E-materialization + d-fold ----------
__global__ __launch_bounds__(512) void k_stats_e(const ushort* __restrict__ bT, const ushort* __restrict__ cT,
                                                 ushort* __restrict__ dmat, ushort* __restrict__ E) {
  __shared__ ushort sCT[3][8192];
  __shared__ float lsum[64];
  int bx = blockIdx.x;
  int b = bx >> 6;
  int IC = bx & 63;
  int i0 = IC * 64;
  int t = threadIdx.x, w = t >> 6, l = t & 63;
  int l31 = l & 31, hi = l >> 5;
  int it_s = w & 1, Jl = w >> 1;
  if (t < 64) lsum[t] = 0.f;
  const ushort* bTb = bT + (size_t)b * 262144;
  const ushort* cTb = cT + (size_t)b * 262144;
  int ri = i0 + 32 * it_s + l31;
  int r7 = ri & 7;
  s16x8 af[4];
#pragma unroll
  for (int kc = 0; kc < 4; ++kc)
    af[kc] = *reinterpret_cast<const s16x8*>(bTb + (size_t)ri * 64 + (((2 * kc + hi) ^ r7) << 3));
  __builtin_amdgcn_sched_barrier(0);   // pin af before staging (vmcnt counting)
  auto STAGE = [&](int st) {
#pragma unroll
    for (int q = 0; q < 2; ++q) {
      int idx = t + 512 * q;
      int row = idx >> 3, u = idx & 7;
      gld16(cTb + (size_t)(st * 128 + row) * 64 + ((u ^ (row & 7)) << 3), &sCT[st % 3][idx * 8]);
    }
  };
  STAGE(0); STAGE(1);
  asm volatile("s_waitcnt vmcnt(2)" ::: "memory");   // af + tile0 done; tile1 in flight
  __syncthreads();

  f32x16 zero16;
#pragma unroll
  for (int r = 0; r < 16; ++r) zero16[r] = 0.f;
  float lacc[16];
#pragma unroll
  for (int r = 0; r < 16; ++r) lacc[r] = 0.f;

  for (int st = 0; st < 32; ++st) {
    if (st + 2 < 32) STAGE(st + 2);
    __builtin_amdgcn_sched_barrier(0);
    const ushort* cbuf = &sCT[st % 3][0];
    int rj = Jl * 32 + l31;
    int j7 = rj & 7;
    f32x16 sv = zero16;
    __builtin_amdgcn_s_setprio(1);
#pragma unroll
    for (int kc = 0; kc < 4; ++kc) {
      s16x8 cfv = *reinterpret_cast<const s16x8*>(cbuf + rj * 64 + (((2 * kc + hi) ^ j7) << 3));
      sv = MFMA32(af[kc], cfv, sv);
    }
    __builtin_amdgcn_s_setprio(0);
    float p[16];
#pragma unroll
    for (int r = 0; r < 16; ++r) { p[r] = pexp(sv[r]); lacc[r] += p[r]; }
    uint x0 = cvtpk(p[0], p[1]),   y0 = cvtpk(p[4], p[5]);
    uint x1 = cvtpk(p[2], p[3]),   y1 = cvtpk(p[6], p[7]);
    uint x2 = cvtpk(p[8], p[9]),   y2 = cvtpk(p[12], p[13]);
    uint x3 = cvtpk(p[10], p[11]), y3 = cvtpk(p[14], p[15]);
    plswap(x0, y0); plswap(x1, y1); plswap(x2, y2); plswap(x3, y3);
    u32x4 pw0 = {x0, x1, y0, y1};
    u32x4 pw1 = {x2, x3, y2, y3};
    int J = st * 4 + Jl;
    size_t fb = (((size_t)b * 64 + IC) * 128 + J) * 4 + 2 * it_s;
    *reinterpret_cast<u32x4*>(E + (fb * 64 + l) * 8)       = pw0;
    *reinterpret_cast<u32x4*>(E + ((fb + 1) * 64 + l) * 8) = pw1;
    asm volatile("s_waitcnt vmcnt(4)" ::: "memory");
    __builtin_amdgcn_s_barrier();
  }
#pragma unroll
  for (int off = 1; off < 32; off <<= 1)
#pragma unroll
    for (int r = 0; r < 16; ++r) lacc[r] += __shfl_xor(lacc[r], off);
  if (l31 == 0) {
#pragma unroll
    for (int r = 0; r < 16; ++r)
      atomicAdd(&lsum[32 * it_s + (r & 3) + 8 * (r >> 2) + 4 * hi], lacc[r]);
  }
  __syncthreads();
  if (t < 64) lsum[t] = 1.0f / fmaxf(lsum[t], 1e-30f);
  __syncthreads();
  int c = t;
  size_t rowb = (size_t)(c >> 5) * 512 + (size_t)(c & 31) * 8;
#pragma unroll
  for (int q = 0; q < 8; ++q) {
    int ic = (i0 >> 4) + (q >> 1);
    size_t idx = (((size_t)b * 256 + ic) * 16) * 512 + rowb + (size_t)(q & 1) * 256;
    s16x8 v = *reinterpret_cast<s16x8*>(dmat + idx);
    s16x8 nv;
#pragma unroll
    for (int e = 0; e < 8; ++e) {
      float f = __builtin_bit_cast(float, ((uint)(ushort)v[e]) << 16) * lsum[q * 8 + e];
      nv[e] = (short)f2bf(f);
    }
    *reinterpret_cast<s16x8*>(dmat + idx) = nv;
  }
}

// ---------- kernel 5e: pure GEMM  Y = d' . E ; out = x + Y ----------
// R13 geometry (block 128c x 128j, grid 512 = 2 blocks/CU, 8 waves 32c x 64j)
// with: dv DIRECT from global (coalesced 1KB, L2-resident d-panel) and E
// TRI-buffered (3 x 16KB LDS), staged 2 iters ahead, counted vmcnt(2) never
// 0 until tail. LDS traffic 80KB/block-iter (was 128KB), footprint 48KB.
__global__ __launch_bounds__(512, 2) void k_attn_e(const ushort* __restrict__ dmat, const ushort* __restrict__ E,
                                                   const float* __restrict__ x, float* __restrict__ out) {
  __shared__ ushort sE[3][8192];    // 3 x 16KB
  int bid = blockIdx.x;             // 512 blocks
  int gid = (bid & 7) * 64 + (bid >> 3);   // XCD-grouped, bijective
  int b = gid >> 7, cb = (gid >> 5) & 3, jB = gid & 31;
  int t = threadIdx.x, w = t >> 6, l = t & 63;
  int l31 = l & 31, hi = l >> 5;
  int cg = w >> 1, jg = w & 1;
  int ctg = cb * 4 + cg;
  f32x16 zero16;
#pragma unroll
  for (int r = 0; r < 16; ++r) zero16[r] = 0.f;
  f32x16 yacc[2];
  yacc[0] = zero16; yacc[1] = zero16;

  auto STAGE = [&](int it) {
    const ushort* ebase = E + ((((size_t)b * 64 + it) * 128 + jB * 4) * 4) * 512;
#pragma unroll
    for (int q = 0; q < 2; ++q) {
      int id = t + 512 * q;
      gld16(ebase + (size_t)id * 8, &sE[it % 3][id * 8]);
    }
  };

  STAGE(0); STAGE(1);
  asm volatile("s_waitcnt vmcnt(2)" ::: "memory");   // tile 0 landed; tile 1 in flight
  __builtin_amdgcn_s_barrier();
  __builtin_amdgcn_sched_barrier(0);

  for (int it = 0; it < 64; ++it) {
    // [a] dv(it): 4 coalesced 1KB loads from L2-resident d-panel
    s16x8 dv[4];
#pragma unroll
    for (int ch = 0; ch < 4; ++ch)
      dv[ch] = *reinterpret_cast<const s16x8*>(
          dmat + ((((size_t)b * 256 + (4 * it + ch)) * 16 + ctg) * 64 + l) * 8);
    __builtin_amdgcn_sched_barrier(0);
    // [b] stage E tile it+2 (2 gld16)
    if (it + 2 < 64) STAGE(it + 2);
    __builtin_amdgcn_sched_barrier(0);
    // [c] pfv from sE[it%3] (valid since stage(it) drained at iter it-1)
    const ushort* eb = &sE[it % 3][0];
    s16x8 pfv[2][4];
#pragma unroll
    for (int jj = 0; jj < 2; ++jj)
#pragma unroll
      for (int ch = 0; ch < 4; ++ch)
        pfv[jj][ch] = *reinterpret_cast<const s16x8*>(
            eb + (((2 * jg + jj) * 4 + ch) * 64 + l) * 8);
    __builtin_amdgcn_sched_barrier(0);
    // [d] queue: stage(it+1)[2], dv[4], stage(it+2)[2] -> vmcnt(2) drains
    // stage(it+1)+dv, keeps stage(it+2) in flight. Tail drains all.
    if (it < 62) { asm volatile("s_waitcnt vmcnt(2)" ::: "memory"); }
    else         { asm volatile("s_waitcnt vmcnt(0)" ::: "memory"); }
    __builtin_amdgcn_sched_barrier(0);
    // [e] PV
    __builtin_amdgcn_s_setprio(1);
#pragma unroll
    for (int ch = 0; ch < 4; ++ch) {
      yacc[0] = MFMA32(dv[ch], pfv[0][ch], yacc[0]);
      yacc[1] = MFMA32(dv[ch], pfv[1][ch], yacc[1]);
    }
    __builtin_amdgcn_s_setprio(0);
    // [f] one barrier/iter: all waves done reading sE[it%3] before any wave's
    // next-iter STAGE (writes buf (it+3)%3 == (it)%3) can be issued.
    __builtin_amdgcn_s_barrier();
  }

  // ---- epilogue: out = x + Y
#pragma unroll
  for (int jj = 0; jj < 2; ++jj) {
#pragma unroll
    for (int r = 0; r < 16; ++r) {
      int row = cb * 128 + cg * 32 + (r & 3) + 8 * (r >> 2) + 4 * hi;
      int col = jB * 128 + (2 * jg + jj) * 32 + l31;
      size_t idx = ((size_t)b * 512 + row) * 4096 + col;
      out[idx] = x[idx] + yacc[jj][r];
    }
  }
}

// ---------- FALLBACK kernel 4f: stats v2 (no E) ----------
__global__ __launch_bounds__(512) void k_stats_f(const ushort* __restrict__ bT, const ushort* __restrict__ cT,
                                                 ushort* __restrict__ dmat) {
  __shared__ ushort sCT[3][8192];
  __shared__ float lsum[64];
  int bx = blockIdx.x;
  int b = bx >> 6;
  int i0 = (bx & 63) * 64;
  int t = threadIdx.x, l = t & 63, w = t >> 6;
  int wm = w >> 1, wn = w & 1, g = l >> 4, l15 = l & 15;
  if (t < 64) lsum[t] = 0.f;
  const ushort* bTb = bT + (size_t)b * 262144;
  const ushort* cTb = cT + (size_t)b * 262144;
  int arow = i0 + 16 * wm + l15;
  int r7 = arow & 7;
  const ushort* abase = bTb + (size_t)arow * 64;
  s16x8 a0 = *reinterpret_cast<const s16x8*>(abase + ((g ^ r7) << 3));
  s16x8 a1 = *reinterpret_cast<const s16x8*>(abase + (((g + 4) ^ r7) << 3));
  auto STAGE = [&](int jt) {
#pragma unroll
    for (int q = 0; q < 2; ++q) {
      int idx = t + 512 * q;
      int row = idx >> 3, u = idx & 7;
      gld16(cTb + (size_t)(jt * 128 + row) * 64 + ((u ^ (row & 7)) << 3), &sCT[jt % 3][idx * 8]);
    }
  };
  STAGE(0); STAGE(1);
  asm volatile("s_waitcnt vmcnt(2)" ::: "memory");
  __syncthreads();
  float lacc[4] = {0.f, 0.f, 0.f, 0.f};
  for (int jt = 0; jt < 32; ++jt) {
    if (jt + 2 < 32) STAGE(jt + 2);
    __builtin_amdgcn_sched_barrier(0);
    const ushort* cbuf = &sCT[jt % 3][0];
#pragma unroll
    for (int nt = 0; nt < 4; ++nt) {
      int row = 64 * wn + 16 * nt + l15;
      int rs = row & 7;
      s16x8 b0 = *reinterpret_cast<const s16x8*>(cbuf + row * 64 + ((g ^ rs) << 3));
      s16x8 b1 = *reinterpret_cast<const s16x8*>(cbuf + row * 64 + (((g + 4) ^ rs) << 3));
      f32x4 s = {0.f, 0.f, 0.f, 0.f};
      s = MFMA_BF16(a0, b0, s);
      s = MFMA_BF16(a1, b1, s);
#pragma unroll
      for (int rr = 0; rr < 4; ++rr) lacc[rr] += pexp(s[rr]);
    }
    if (jt < 30) { asm volatile("s_waitcnt vmcnt(2)" ::: "memory"); }
    else         { asm volatile("s_waitcnt vmcnt(0)" ::: "memory"); }
    __builtin_amdgcn_s_barrier();
  }
#pragma unroll
  for (int off = 1; off < 16; off <<= 1)
#pragma unroll
    for (int rr = 0; rr < 4; ++rr) lacc[rr] += __shfl_xor(lacc[rr], off);
  if (l15 == 0) {
#pragma unroll
    for (int rr = 0; rr < 4; ++rr) atomicAdd(&lsum[16 * wm + 4 * g + rr], lacc[rr]);
  }
  __syncthreads();
  if (t < 64) lsum[t] = 1.0f / fmaxf(lsum[t], 1e-30f);
  __syncthreads();
  int c = t;
  size_t rowb = (size_t)(c >> 5) * 512 + (size_t)(c & 31) * 8;
#pragma unroll
  for (int q = 0; q < 8; ++q) {
    int ic = (i0 >> 4) + (q >> 1);
    size_t idx = (((size_t)b * 256 + ic) * 16) * 512 + rowb + (size_t)(q & 1) * 256;
    s16x8 v = *reinterpret_cast<s16x8*>(dmat + idx);
    s16x8 nv;
#pragma unroll
    for (int e = 0; e < 8; ++e) {
      float f = __builtin_bit_cast(float, ((uint)(ushort)v[e]) << 16) * lsum[q * 8 + e];
      nv[e] = (short)f2bf(f);
    }
    *reinterpret_cast<s16x8*>(dmat + idx) = nv;
  }
}

// ---------- FALLBACK kernel 5f: R10 fused attn ----------
__global__ __launch_bounds__(512, 2) void k_attn_f(const ushort* __restrict__ bT, const ushort* __restrict__ cT,
                                                   const ushort* __restrict__ dmat,
                                                   const float* __restrict__ x, float* __restrict__ out) {
  __shared__ ushort sBT[3][4096];
  __shared__ ushort sP[2][8192];
  int bid = blockIdx.x;
  int gid = (bid & 7) * 64 + (bid >> 3);
  int b   = gid >> 7;
  int cb  = (gid >> 5) & 3;
  int jB  = gid & 31;
  int t = threadIdx.x, w = t >> 6, l = t & 63;
  int l31 = l & 31, hi = l >> 5;
  int it_s = w >> 2, jt_s = w & 3;
  int cg = w >> 1, jg = w & 1;
  const ushort* bTb = bT + (size_t)b * 262144;
  const ushort* cTb = cT + (size_t)b * 262144;
  int js = jB * 128 + jt_s * 32 + l31;
  s16x8 cf[4];
#pragma unroll
  for (int kc = 0; kc < 4; ++kc)
    cf[kc] = *reinterpret_cast<const s16x8*>(cTb + (size_t)js * 64 + kc * 16 + hi * 8);
  int ctg = cb * 4 + cg;
  f32x16 zero16;
#pragma unroll
  for (int r = 0; r < 16; ++r) zero16[r] = 0.f;
  f32x16 yacc[2];
  yacc[0] = zero16; yacc[1] = zero16;
  auto STAGE = [&](int it) {
    gld16(bTb + (size_t)it * 4096 + (size_t)t * 8, &sBT[it % 3][t * 8]);
  };
  STAGE(0); STAGE(1);
  asm volatile("s_waitcnt vmcnt(1)" ::: "memory");
  __builtin_amdgcn_s_barrier();
  __builtin_amdgcn_sched_barrier(0);
  for (int it = 0; it < 64; ++it) {
    s16x8 dv[4];
#pragma unroll
    for (int ch = 0; ch < 4; ++ch)
      dv[ch] = *reinterpret_cast<const s16x8*>(
          dmat + ((((size_t)b * 256 + (4 * it + ch)) * 16 + ctg) * 64 + l) * 8);
    if (it + 2 < 64) STAGE(it + 2);
    __builtin_amdgcn_sched_barrier(0);
    const ushort* bbuf = &sBT[it % 3][0];
    f32x16 sv = zero16;
    __builtin_amdgcn_s_setprio(1);
#pragma unroll
    for (int kc = 0; kc < 4; ++kc) {
      const s16x8 bfv = *reinterpret_cast<const s16x8*>(
          bbuf + (32 * it_s + l31) * 64 + (((2 * kc + hi) ^ (l31 & 7)) << 3));
      sv = MFMA32(bfv, cf[kc], sv);
    }
    __builtin_amdgcn_s_setprio(0);
    float p[16];
#pragma unroll
    for (int r = 0; r < 16; ++r) p[r] = pexp(sv[r]);
    uint x0 = cvtpk(p[0], p[1]),   y0 = cvtpk(p[4], p[5]);
    uint x1 = cvtpk(p[2], p[3]),   y1 = cvtpk(p[6], p[7]);
    uint x2 = cvtpk(p[8], p[9]),   y2 = cvtpk(p[12], p[13]);
    uint x3 = cvtpk(p[10], p[11]), y3 = cvtpk(p[14], p[15]);
    plswap(x0, y0); plswap(x1, y1); plswap(x2, y2); plswap(x3, y3);
    u32x4 pw0 = {x0, x1, y0, y1};
    u32x4 pw1 = {x2, x3, y2, y3};
    ushort* pbuf = &sP[it & 1][0];
    int fi0 = jt_s * 4 + 2 * it_s;
    *reinterpret_cast<s16x8*>(pbuf + (fi0 * 64 + l) * 8)       = __builtin_bit_cast(s16x8, pw0);
    *reinterpret_cast<s16x8*>(pbuf + ((fi0 + 1) * 64 + l) * 8) = __builtin_bit_cast(s16x8, pw1);
    asm volatile("s_waitcnt lgkmcnt(0)" ::: "memory");
    __builtin_amdgcn_s_barrier();
    if (it < 62) { asm volatile("s_waitcnt vmcnt(1)" ::: "memory"); }
    else         { asm volatile("s_waitcnt vmcnt(0)" ::: "memory"); }
    __builtin_amdgcn_sched_barrier(0);
    __builtin_amdgcn_s_setprio(1);
#pragma unroll
    for (int ch = 0; ch < 4; ++ch) {
#pragma unroll
      for (int jj = 0; jj < 2; ++jj) {
        int jt = 2 * jg + jj;
        const s16x8 pfv = *reinterpret_cast<const s16x8*>(pbuf + ((jt * 4 + ch) * 64 + l) * 8);
        yacc[jj] = MFMA32(dv[ch], pfv, yacc[jj]);
      }
    }
    __builtin_amdgcn_s_setprio(0);
  }
#pragma unroll
  for (int jj = 0; jj < 2; ++jj) {
#pragma unroll
    for (int r = 0; r < 16; ++r) {
      int row = cb * 128 + cg * 32 + (r & 3) + 8 * (r >> 2) + 4 * hi;
      int col = jB * 128 + (2 * jg + jj) * 32 + l31;
      size_t idx = ((size_t)b * 512 + row) * 4096 + col;
      out[idx] = x[idx] + yacc[jj][r];
    }
  }
}

extern "C" void kernel_launch(void* const* d_in, const int* in_sizes, int n_in,
                              void* d_out, int out_size, void* d_ws, size_t ws_size,
                              hipStream_t stream) {
  const float* x  = (const float*)d_in[0];
  const float* Wb = (const float*)d_in[1];
  const float* bb = (const float*)d_in[2];
  const float* Wc = (const float*)d_in[3];
  const float* bc = (const float*)d_in[4];
  const float* Wd = (const float*)d_in[5];
  const float* bd = (const float*)d_in[6];
  char* ws = (char*)d_ws;
  ushort* xT   = (ushort*)(ws + WS_XT);
  ushort* dmat = (ushort*)(ws + WS_D);
  ushort* bT   = (ushort*)(ws + WS_BT);
  ushort* cT   = (ushort*)(ws + WS_CT);
  ushort* Wcat = (ushort*)(ws + WS_WCAT);
  float*  bcat = (float*)(ws + WS_BCAT);
  ushort* E    = (ushort*)(ws + WS_E);
  float*  out  = (float*)d_out;

  k_prep_w<<<1280, 256, 0, stream>>>(Wb, bb, Wc, bc, Wd, bd, Wcat, bcat);
  k_prep_xt<<<2048, 256, 0, stream>>>(x, xT);
  k_proj<<<640, 256, 0, stream>>>(Wcat, bcat, xT, bT, cT, dmat);
  if (ws_size >= WS_E_NEED) {
    k_stats_e<<<256, 512, 0, stream>>>(bT, cT, dmat, E);
    k_attn_e<<<512, 512, 0, stream>>>(dmat, E, x, out);
  } else {
    k_stats_f<<<256, 512, 0, stream>>>(bT, cT, dmat);
    k_attn_f<<<512, 512, 0, stream>>>(bT, cT, dmat, x, out);
  }
}

// Round 16
// 185.165 us; speedup vs baseline: 1.0493x; 1.0493x over previous
//
#include <hip/hip_runtime.h>
#include <hip/hip_bf16.h>

typedef float f32x4 __attribute__((ext_vector_type(4)));
typedef float f32x16 __attribute__((ext_vector_type(16)));
typedef short s16x8 __attribute__((ext_vector_type(8)));
typedef uint  u32x4 __attribute__((ext_vector_type(4)));

#define MFMA_BF16(a, b, c) __builtin_amdgcn_mfma_f32_16x16x32_bf16((a), (b), (c), 0, 0, 0)
#define MFMA32(a, b, c)    __builtin_amdgcn_mfma_f32_32x32x16_bf16((a), (b), (c), 0, 0, 0)

// ---------- helpers ----------
__device__ __forceinline__ ushort f2bf(float f) {
  uint u = __builtin_bit_cast(uint, f);
  u += 0x7FFFu + ((u >> 16) & 1u);
  return (ushort)(u >> 16);
}
__device__ __forceinline__ uint pack2bf(float a, float b) {
  return (uint)f2bf(a) | ((uint)f2bf(b) << 16);
}
// exp(s - 30) = exp2(fma(s, log2e, -30*log2e))
__device__ __forceinline__ float pexp(float s) {
  float t = fmaf(s, 1.4426950408889634f, -43.2808512266689f);
  float r;
  asm("v_exp_f32 %0, %1" : "=v"(r) : "v"(t));
  return r;
}
__device__ __forceinline__ uint cvtpk(float lo, float hi) {
  uint r;
  asm("v_cvt_pk_bf16_f32 %0, %1, %2" : "=v"(r) : "v"(lo), "v"(hi));
  return r;
}
__device__ __forceinline__ void plswap(uint& a, uint& b) {
  asm("v_permlane32_swap_b32 %0, %1" : "+v"(a), "+v"(b));
}
__device__ __forceinline__ void gld16(const void* g, void* l) {
  __builtin_amdgcn_global_load_lds(
      (const __attribute__((address_space(1))) unsigned int*)g,
      (__attribute__((address_space(3))) unsigned int*)l, 16, 0, 0);
}

// ---------- ws layout (bytes) ----------
// dmat FRAGMENT-MAJOR: elem (b,c,i) at ((((b*256 + (i>>4))*16 + (c>>5))*64
//                                        + ((i>>3)&1)*32 + (c&31))*8 + (i&7)
// bT rows unit-swizzled: 16B unit u at row i stored at u^(i&7)
// E: frag-major exp(S-30) bf16: frag f = (((b*64 + IC)*128 + J)*4 + ch),
//    elem (f*64 + lane)*8 + e
#define WS_XT    0UL
#define WS_D     16777216UL
#define WS_BT    33554432UL
#define WS_CT    35651584UL
#define WS_WCAT  37748736UL
#define WS_BCAT  38404096UL
#define WS_E     41943040UL
#define WS_E_NEED (WS_E + 134217728UL)

// ---------- kernel 1: pack weights to bf16 [640][512] + bias concat ----------
__global__ void k_prep_w(const float* __restrict__ Wb, const float* __restrict__ bb,
                         const float* __restrict__ Wc, const float* __restrict__ bc,
                         const float* __restrict__ Wd, const float* __restrict__ bd,
                         ushort* __restrict__ Wcat, float* __restrict__ bcat) {
  int idx = blockIdx.x * 256 + threadIdx.x;
  if (idx < 640 * 512) {
    int m = idx >> 9, k = idx & 511;
    float v = (m < 64) ? Wb[m * 512 + k] : (m < 128) ? Wc[(m - 64) * 512 + k] : Wd[(m - 128) * 512 + k];
    Wcat[idx] = f2bf(v);
  }
  if (idx < 640) {
    bcat[idx] = (idx < 64) ? bb[idx] : (idx < 128) ? bc[idx - 64] : bd[idx - 128];
  }
}

// ---------- kernel 2: transpose x [B][512][4096] f32 -> xT [B][4096][512] bf16 ----------
__global__ __launch_bounds__(256) void k_prep_xt(const float* __restrict__ x, ushort* __restrict__ xT) {
  __shared__ float tile[64][65];
  int bx = blockIdx.x;
  int b = bx >> 9;                  // 8*64 = 512 tiles per batch
  int c0 = ((bx >> 6) & 7) * 64;
  int n0 = (bx & 63) * 64;
  int t = threadIdx.x;
  const float* xb = x + (size_t)b * 512 * 4096;
#pragma unroll
  for (int p = 0; p < 4; ++p) {
    int cl = (t >> 4) + 16 * p;
    int nf = (t & 15) * 4;
    float4 v = *reinterpret_cast<const float4*>(xb + (size_t)(c0 + cl) * 4096 + n0 + nf);
    tile[cl][nf + 0] = v.x; tile[cl][nf + 1] = v.y; tile[cl][nf + 2] = v.z; tile[cl][nf + 3] = v.w;
  }
  __syncthreads();
  ushort* dst = xT + (size_t)b * 4096 * 512;
#pragma unroll
  for (int q = 0; q < 2; ++q) {
    int ch = t + 256 * q;
    int nl = ch >> 3;
    int cf = (ch & 7) * 8;
    uint4 o;
    o.x = pack2bf(tile[cf + 0][nl], tile[cf + 1][nl]);
    o.y = pack2bf(tile[cf + 2][nl], tile[cf + 3][nl]);
    o.z = pack2bf(tile[cf + 4][nl], tile[cf + 5][nl]);
    o.w = pack2bf(tile[cf + 6][nl], tile[cf + 7][nl]);
    *reinterpret_cast<uint4*>(dst + (size_t)(n0 + nl) * 512 + c0 + cf) = o;
  }
}

// ---------- kernel 3: projection GEMM [640 x 4096, K=512] per batch ----------
__global__ __launch_bounds__(256) void k_proj(const ushort* __restrict__ Wcat, const float* __restrict__ bcat,
                                              const ushort* __restrict__ xT, ushort* __restrict__ bT,
                                              ushort* __restrict__ cT, ushort* __restrict__ dmat) {
  int bx = blockIdx.x;
  int b = bx / 160;
  int r = bx % 160;
  int m0 = (r >> 5) * 128;    // 5 m-tiles
  int n0 = (r & 31) * 128;    // 32 n-tiles
  int t = threadIdx.x, l = t & 63, w = t >> 6;
  int wm = w >> 1, wn = w & 1, g = l >> 4, l15 = l & 15;
  const ushort* xb = xT + (size_t)b * 4096 * 512;
  f32x4 acc[4][4] = {};
  s16x8 bfn[4];
#pragma unroll
  for (int nt = 0; nt < 4; ++nt)
    bfn[nt] = *reinterpret_cast<const s16x8*>(xb + (size_t)(n0 + 64 * wn + 16 * nt + l15) * 512 + 8 * g);
  for (int k0 = 0; k0 < 512; k0 += 32) {
    s16x8 a[4], bf[4];
#pragma unroll
    for (int nt = 0; nt < 4; ++nt) bf[nt] = bfn[nt];
#pragma unroll
    for (int mt = 0; mt < 4; ++mt)
      a[mt] = *reinterpret_cast<const s16x8*>(Wcat + (size_t)(m0 + 64 * wm + 16 * mt + l15) * 512 + k0 + 8 * g);
    if (k0 + 32 < 512) {
#pragma unroll
      for (int nt = 0; nt < 4; ++nt)
        bfn[nt] = *reinterpret_cast<const s16x8*>(xb + (size_t)(n0 + 64 * wn + 16 * nt + l15) * 512 + k0 + 32 + 8 * g);
    }
    __builtin_amdgcn_sched_barrier(0);
#pragma unroll
    for (int mt = 0; mt < 4; ++mt)
#pragma unroll
      for (int nt = 0; nt < 4; ++nt)
        acc[mt][nt] = MFMA_BF16(a[mt], bf[nt], acc[mt][nt]);
  }
#pragma unroll
  for (int mt = 0; mt < 4; ++mt) {
    int mbase = m0 + 64 * wm + 16 * mt + 4 * g;
#pragma unroll
    for (int nt = 0; nt < 4; ++nt) {
      int n = n0 + 64 * wn + 16 * nt + l15;
      float vv[4];
      vv[0] = acc[mt][nt][0] + bcat[mbase + 0];
      vv[1] = acc[mt][nt][1] + bcat[mbase + 1];
      vv[2] = acc[mt][nt][2] + bcat[mbase + 2];
      vv[3] = acc[mt][nt][3] + bcat[mbase + 3];
      if (mbase < 64) {
        // bT swizzled: unit u=mbase>>3 stored at u^(n&7); mbase&4 selects 8B half
        uint2 u2; u2.x = pack2bf(vv[0], vv[1]); u2.y = pack2bf(vv[2], vv[3]);
        size_t off = ((size_t)b * 4096 + n) * 64 + (size_t)((((mbase >> 3) ^ (n & 7)) << 3) + (mbase & 4));
        *reinterpret_cast<uint2*>(bT + off) = u2;
      } else if (mbase < 128) {
        uint2 u2; u2.x = pack2bf(vv[0], vv[1]); u2.y = pack2bf(vv[2], vv[3]);
        *reinterpret_cast<uint2*>(cT + ((size_t)b * 4096 + n) * 64 + (mbase - 64)) = u2;
      } else {
        // d fragment-major: (b, c, i=n)
        int cc = mbase - 128;
        size_t fb = (((size_t)b * 256 + (n >> 4)) * 16) * 512;  // *64 lanes *8 elems
#pragma unroll
        for (int rr = 0; rr < 4; ++rr) {
          int c = cc + rr;
          size_t idx = fb + (size_t)(c >> 5) * 512 + (size_t)(((n >> 3) & 1) * 32 + (c & 31)) * 8 + (n & 7);
          dmat[idx] = f2bf(vv[rr]);
        }
      }
    }
  }
}

// ---------- kernel 4e: stats + E-materialization + d-fold ----------
__global__ __launch_bounds__(512) void k_stats_e(const ushort* __restrict__ bT, const ushort* __restrict__ cT,
                                                 ushort* __restrict__ dmat, ushort* __restrict__ E) {
  __shared__ ushort sCT[3][8192];
  __shared__ float lsum[64];
  int bx = blockIdx.x;
  int b = bx >> 6;
  int IC = bx & 63;
  int i0 = IC * 64;
  int t = threadIdx.x, w = t >> 6, l = t & 63;
  int l31 = l & 31, hi = l >> 5;
  int it_s = w & 1, Jl = w >> 1;
  if (t < 64) lsum[t] = 0.f;
  const ushort* bTb = bT + (size_t)b * 262144;
  const ushort* cTb = cT + (size_t)b * 262144;
  int ri = i0 + 32 * it_s + l31;
  int r7 = ri & 7;
  s16x8 af[4];
#pragma unroll
  for (int kc = 0; kc < 4; ++kc)
    af[kc] = *reinterpret_cast<const s16x8*>(bTb + (size_t)ri * 64 + (((2 * kc + hi) ^ r7) << 3));
  __builtin_amdgcn_sched_barrier(0);   // pin af before staging (vmcnt counting)
  auto STAGE = [&](int st) {
#pragma unroll
    for (int q = 0; q < 2; ++q) {
      int idx = t + 512 * q;
      int row = idx >> 3, u = idx & 7;
      gld16(cTb + (size_t)(st * 128 + row) * 64 + ((u ^ (row & 7)) << 3), &sCT[st % 3][idx * 8]);
    }
  };
  STAGE(0); STAGE(1);
  asm volatile("s_waitcnt vmcnt(2)" ::: "memory");   // af + tile0 done; tile1 in flight
  __syncthreads();

  f32x16 zero16;
#pragma unroll
  for (int r = 0; r < 16; ++r) zero16[r] = 0.f;
  float lacc[16];
#pragma unroll
  for (int r = 0; r < 16; ++r) lacc[r] = 0.f;

  for (int st = 0; st < 32; ++st) {
    if (st + 2 < 32) STAGE(st + 2);
    __builtin_amdgcn_sched_barrier(0);
    const ushort* cbuf = &sCT[st % 3][0];
    int rj = Jl * 32 + l31;
    int j7 = rj & 7;
    f32x16 sv = zero16;
    __builtin_amdgcn_s_setprio(1);
#pragma unroll
    for (int kc = 0; kc < 4; ++kc) {
      s16x8 cfv = *reinterpret_cast<const s16x8*>(cbuf + rj * 64 + (((2 * kc + hi) ^ j7) << 3));
      sv = MFMA32(af[kc], cfv, sv);
    }
    __builtin_amdgcn_s_setprio(0);
    float p[16];
#pragma unroll
    for (int r = 0; r < 16; ++r) { p[r] = pexp(sv[r]); lacc[r] += p[r]; }
    uint x0 = cvtpk(p[0], p[1]),   y0 = cvtpk(p[4], p[5]);
    uint x1 = cvtpk(p[2], p[3]),   y1 = cvtpk(p[6], p[7]);
    uint x2 = cvtpk(p[8], p[9]),   y2 = cvtpk(p[12], p[13]);
    uint x3 = cvtpk(p[10], p[11]), y3 = cvtpk(p[14], p[15]);
    plswap(x0, y0); plswap(x1, y1); plswap(x2, y2); plswap(x3, y3);
    u32x4 pw0 = {x0, x1, y0, y1};
    u32x4 pw1 = {x2, x3, y2, y3};
    int J = st * 4 + Jl;
    size_t fb = (((size_t)b * 64 + IC) * 128 + J) * 4 + 2 * it_s;
    *reinterpret_cast<u32x4*>(E + (fb * 64 + l) * 8)       = pw0;
    *reinterpret_cast<u32x4*>(E + ((fb + 1) * 64 + l) * 8) = pw1;
    asm volatile("s_waitcnt vmcnt(4)" ::: "memory");
    __builtin_amdgcn_s_barrier();
  }
#pragma unroll
  for (int off = 1; off < 32; off <<= 1)
#pragma unroll
    for (int r = 0; r < 16; ++r) lacc[r] += __shfl_xor(lacc[r], off);
  if (l31 == 0) {
#pragma unroll
    for (int r = 0; r < 16; ++r)
      atomicAdd(&lsum[32 * it_s + (r & 3) + 8 * (r >> 2) + 4 * hi], lacc[r]);
  }
  __syncthreads();
  if (t < 64) lsum[t] = 1.0f / fmaxf(lsum[t], 1e-30f);
  __syncthreads();
  int c = t;
  size_t rowb = (size_t)(c >> 5) * 512 + (size_t)(c & 31) * 8;
#pragma unroll
  for (int q = 0; q < 8; ++q) {
    int ic = (i0 >> 4) + (q >> 1);
    size_t idx = (((size_t)b * 256 + ic) * 16) * 512 + rowb + (size_t)(q & 1) * 256;
    s16x8 v = *reinterpret_cast<s16x8*>(dmat + idx);
    s16x8 nv;
#pragma unroll
    for (int e = 0; e < 8; ++e) {
      float f = __builtin_bit_cast(float, ((uint)(ushort)v[e]) << 16) * lsum[q * 8 + e];
      nv[e] = (short)f2bf(f);
    }
    *reinterpret_cast<s16x8*>(dmat + idx) = nv;
  }
}

// ---------- kernel 5e: pure GEMM  Y = d' . E ; out = x + Y ----------
// (R13 known-good: 87.8 us.) Block (b, cb:128c, jB:128j), 8 waves, wave=(cg,jg):
// 32c x 64j. Per iter: dbuf-staged E-tile (16KB) + d-tile (16KB) via gld16;
// 12 frag ds_reads + 8 MFMA32 per wave; one barrier. No exp/pack/score work.
__global__ __launch_bounds__(512, 2) void k_attn_e(const ushort* __restrict__ dmat, const ushort* __restrict__ E,
                                                   const float* __restrict__ x, float* __restrict__ out) {
  __shared__ ushort sE[2][8192];
  __shared__ ushort sD[2][8192];
  int bid = blockIdx.x;
  int gid = (bid & 7) * 64 + (bid >> 3);   // XCD-grouped, bijective
  int b = gid >> 7, cb = (gid >> 5) & 3, jB = gid & 31;
  int t = threadIdx.x, w = t >> 6, l = t & 63;
  int l31 = l & 31, hi = l >> 5;
  int cg = w >> 1, jg = w & 1;
  f32x16 zero16;
#pragma unroll
  for (int r = 0; r < 16; ++r) zero16[r] = 0.f;
  f32x16 yacc[2];
  yacc[0] = zero16; yacc[1] = zero16;

  auto STAGE = [&](int buf, int it) {
    const ushort* ebase = E + ((((size_t)b * 64 + it) * 128 + jB * 4) * 4) * 512;
    const ushort* dbase = dmat + (((size_t)b * 256 + 4 * it) * 16 + cb * 4) * 512;
#pragma unroll
    for (int q = 0; q < 2; ++q) {
      int id = t + 512 * q;
      gld16(ebase + (size_t)id * 8, &sE[buf][id * 8]);
    }
#pragma unroll
    for (int q = 0; q < 2; ++q) {
      int id = t + 512 * q;
      gld16(dbase + (size_t)(id >> 8) * 8192 + (size_t)(id & 255) * 8, &sD[buf][id * 8]);
    }
  };

  STAGE(0, 0);
  asm volatile("s_waitcnt vmcnt(0)" ::: "memory");
  __builtin_amdgcn_s_barrier();
  __builtin_amdgcn_sched_barrier(0);

  int buf = 0;
  for (int it = 0; it < 64; ++it) {
    if (it + 1 < 64) STAGE(buf ^ 1, it + 1);
    __builtin_amdgcn_sched_barrier(0);
    const ushort* eb = &sE[buf][0];
    const ushort* db = &sD[buf][0];
    s16x8 dv[4];
#pragma unroll
    for (int ch = 0; ch < 4; ++ch)
      dv[ch] = *reinterpret_cast<const s16x8*>(db + ((ch * 4 + cg) * 64 + l) * 8);
    __builtin_amdgcn_s_setprio(1);
#pragma unroll
    for (int ch = 0; ch < 4; ++ch) {
#pragma unroll
      for (int jj = 0; jj < 2; ++jj) {
        s16x8 pfv = *reinterpret_cast<const s16x8*>(eb + (((2 * jg + jj) * 4 + ch) * 64 + l) * 8);
        yacc[jj] = MFMA32(dv[ch], pfv, yacc[jj]);
      }
    }
    __builtin_amdgcn_s_setprio(0);
    __builtin_amdgcn_sched_barrier(0);
    asm volatile("s_waitcnt vmcnt(0)" ::: "memory");   // next tile landed
    __builtin_amdgcn_s_barrier();
    buf ^= 1;
  }
  // ---- epilogue: out = x + Y
#pragma unroll
  for (int jj = 0; jj < 2; ++jj) {
#pragma unroll
    for (int r = 0; r < 16; ++r) {
      int row = cb * 128 + cg * 32 + (r & 3) + 8 * (r >> 2) + 4 * hi;
      int col = jB * 128 + (2 * jg + jj) * 32 + l31;
      size_t idx = ((size_t)b * 512 + row) * 4096 + col;
      out[idx] = x[idx] + yacc[jj][r];
    }
  }
}

// ---------- FALLBACK kernel 4f: stats v2 (no E) ----------
__global__ __launch_bounds__(512) void k_stats_f(const ushort* __restrict__ bT, const ushort* __restrict__ cT,
                                                 ushort* __restrict__ dmat) {
  __shared__ ushort sCT[3][8192];
  __shared__ float lsum[64];
  int bx = blockIdx.x;
  int b = bx >> 6;
  int i0 = (bx & 63) * 64;
  int t = threadIdx.x, l = t & 63, w = t >> 6;
  int wm = w >> 1, wn = w & 1, g = l >> 4, l15 = l & 15;
  if (t < 64) lsum[t] = 0.f;
  const ushort* bTb = bT + (size_t)b * 262144;
  const ushort* cTb = cT + (size_t)b * 262144;
  int arow = i0 + 16 * wm + l15;
  int r7 = arow & 7;
  const ushort* abase = bTb + (size_t)arow * 64;
  s16x8 a0 = *reinterpret_cast<const s16x8*>(abase + ((g ^ r7) << 3));
  s16x8 a1 = *reinterpret_cast<const s16x8*>(abase + (((g + 4) ^ r7) << 3));
  auto STAGE = [&](int jt) {
#pragma unroll
    for (int q = 0; q < 2; ++q) {
      int idx = t + 512 * q;
      int row = idx >> 3, u = idx & 7;
      gld16(cTb + (size_t)(jt * 128 + row) * 64 + ((u ^ (row & 7)) << 3), &sCT[jt % 3][idx * 8]);
    }
  };
  STAGE(0); STAGE(1);
  asm volatile("s_waitcnt vmcnt(2)" ::: "memory");
  __syncthreads();
  float lacc[4] = {0.f, 0.f, 0.f, 0.f};
  for (int jt = 0; jt < 32; ++jt) {
    if (jt + 2 < 32) STAGE(jt + 2);
    __builtin_amdgcn_sched_barrier(0);
    const ushort* cbuf = &sCT[jt % 3][0];
#pragma unroll
    for (int nt = 0; nt < 4; ++nt) {
      int row = 64 * wn + 16 * nt + l15;
      int rs = row & 7;
      s16x8 b0 = *reinterpret_cast<const s16x8*>(cbuf + row * 64 + ((g ^ rs) << 3));
      s16x8 b1 = *reinterpret_cast<const s16x8*>(cbuf + row * 64 + (((g + 4) ^ rs) << 3));
      f32x4 s = {0.f, 0.f, 0.f, 0.f};
      s = MFMA_BF16(a0, b0, s);
      s = MFMA_BF16(a1, b1, s);
#pragma unroll
      for (int rr = 0; rr < 4; ++rr) lacc[rr] += pexp(s[rr]);
    }
    if (jt < 30) { asm volatile("s_waitcnt vmcnt(2)" ::: "memory"); }
    else         { asm volatile("s_waitcnt vmcnt(0)" ::: "memory"); }
    __builtin_amdgcn_s_barrier();
  }
#pragma unroll
  for (int off = 1; off < 16; off <<= 1)
#pragma unroll
    for (int rr = 0; rr < 4; ++rr) lacc[rr] += __shfl_xor(lacc[rr], off);
  if (l15 == 0) {
#pragma unroll
    for (int rr = 0; rr < 4; ++rr) atomicAdd(&lsum[16 * wm + 4 * g + rr], lacc[rr]);
  }
  __syncthreads();
  if (t < 64) lsum[t] = 1.0f / fmaxf(lsum[t], 1e-30f);
  __syncthreads();
  int c = t;
  size_t rowb = (size_t)(c >> 5) * 512 + (size_t)(c & 31) * 8;
#pragma unroll
  for (int q = 0; q < 8; ++q) {
    int ic = (i0 >> 4) + (q >> 1);
    size_t idx = (((size_t)b * 256 + ic) * 16) * 512 + rowb + (size_t)(q & 1) * 256;
    s16x8 v = *reinterpret_cast<s16x8*>(dmat + idx);
    s16x8 nv;
#pragma unroll
    for (int e = 0; e < 8; ++e) {
      float f = __builtin_bit_cast(float, ((uint)(ushort)v[e]) << 16) * lsum[q * 8 + e];
      nv[e] = (short)f2bf(f);
    }
    *reinterpret_cast<s16x8*>(dmat + idx) = nv;
  }
}

// ---------- FALLBACK kernel 5f: R10 fused attn ----------
__global__ __launch_bounds__(512, 2) void k_attn_f(const ushort* __restrict__ bT, const ushort* __restrict__ cT,
                                                   const ushort* __restrict__ dmat,
                                                   const float* __restrict__ x, float* __restrict__ out) {
  __shared__ ushort sBT[3][4096];
  __shared__ ushort sP[2][8192];
  int bid = blockIdx.x;
  int gid = (bid & 7) * 64 + (bid >> 3);
  int b   = gid >> 7;
  int cb  = (gid >> 5) & 3;
  int jB  = gid & 31;
  int t = threadIdx.x, w = t >> 6, l = t & 63;
  int l31 = l & 31, hi = l >> 5;
  int it_s = w >> 2, jt_s = w & 3;
  int cg = w >> 1, jg = w & 1;
  const ushort* bTb = bT + (size_t)b * 262144;
  const ushort* cTb = cT + (size_t)b * 262144;
  int js = jB * 128 + jt_s * 32 + l31;
  s16x8 cf[4];
#pragma unroll
  for (int kc = 0; kc < 4; ++kc)
    cf[kc] = *reinterpret_cast<const s16x8*>(cTb + (size_t)js * 64 + kc * 16 + hi * 8);
  int ctg = cb * 4 + cg;
  f32x16 zero16;
#pragma unroll
  for (int r = 0; r < 16; ++r) zero16[r] = 0.f;
  f32x16 yacc[2];
  yacc[0] = zero16; yacc[1] = zero16;
  auto STAGE = [&](int it) {
    gld16(bTb + (size_t)it * 4096 + (size_t)t * 8, &sBT[it % 3][t * 8]);
  };
  STAGE(0); STAGE(1);
  asm volatile("s_waitcnt vmcnt(1)" ::: "memory");
  __builtin_amdgcn_s_barrier();
  __builtin_amdgcn_sched_barrier(0);
  for (int it = 0; it < 64; ++it) {
    s16x8 dv[4];
#pragma unroll
    for (int ch = 0; ch < 4; ++ch)
      dv[ch] = *reinterpret_cast<const s16x8*>(
          dmat + ((((size_t)b * 256 + (4 * it + ch)) * 16 + ctg) * 64 + l) * 8);
    if (it + 2 < 64) STAGE(it + 2);
    __builtin_amdgcn_sched_barrier(0);
    const ushort* bbuf = &sBT[it % 3][0];
    f32x16 sv = zero16;
    __builtin_amdgcn_s_setprio(1);
#pragma unroll
    for (int kc = 0; kc < 4; ++kc) {
      const s16x8 bfv = *reinterpret_cast<const s16x8*>(
          bbuf + (32 * it_s + l31) * 64 + (((2 * kc + hi) ^ (l31 & 7)) << 3));
      sv = MFMA32(bfv, cf[kc], sv);
    }
    __builtin_amdgcn_s_setprio(0);
    float p[16];
#pragma unroll
    for (int r = 0; r < 16; ++r) p[r] = pexp(sv[r]);
    uint x0 = cvtpk(p[0], p[1]),   y0 = cvtpk(p[4], p[5]);
    uint x1 = cvtpk(p[2], p[3]),   y1 = cvtpk(p[6], p[7]);
    uint x2 = cvtpk(p[8], p[9]),   y2 = cvtpk(p[12], p[13]);
    uint x3 = cvtpk(p[10], p[11]), y3 = cvtpk(p[14], p[15]);
    plswap(x0, y0); plswap(x1, y1); plswap(x2, y2); plswap(x3, y3);
    u32x4 pw0 = {x0, x1, y0, y1};
    u32x4 pw1 = {x2, x3, y2, y3};
    ushort* pbuf = &sP[it & 1][0];
    int fi0 = jt_s * 4 + 2 * it_s;
    *reinterpret_cast<s16x8*>(pbuf + (fi0 * 64 + l) * 8)       = __builtin_bit_cast(s16x8, pw0);
    *reinterpret_cast<s16x8*>(pbuf + ((fi0 + 1) * 64 + l) * 8) = __builtin_bit_cast(s16x8, pw1);
    asm volatile("s_waitcnt lgkmcnt(0)" ::: "memory");
    __builtin_amdgcn_s_barrier();
    if (it < 62) { asm volatile("s_waitcnt vmcnt(1)" ::: "memory"); }
    else         { asm volatile("s_waitcnt vmcnt(0)" ::: "memory"); }
    __builtin_amdgcn_sched_barrier(0);
    __builtin_amdgcn_s_setprio(1);
#pragma unroll
    for (int ch = 0; ch < 4; ++ch) {
#pragma unroll
      for (int jj = 0; jj < 2; ++jj) {
        int jt = 2 * jg + jj;
        const s16x8 pfv = *reinterpret_cast<const s16x8*>(pbuf + ((jt * 4 + ch) * 64 + l) * 8);
        yacc[jj] = MFMA32(dv[ch], pfv, yacc[jj]);
      }
    }
    __builtin_amdgcn_s_setprio(0);
  }
#pragma unroll
  for (int jj = 0; jj < 2; ++jj) {
#pragma unroll
    for (int r = 0; r < 16; ++r) {
      int row = cb * 128 + cg * 32 + (r & 3) + 8 * (r >> 2) + 4 * hi;
      int col = jB * 128 + (2 * jg + jj) * 32 + l31;
      size_t idx = ((size_t)b * 512 + row) * 4096 + col;
      out[idx] = x[idx] + yacc[jj][r];
    }
  }
}

extern "C" void kernel_launch(void* const* d_in, const int* in_sizes, int n_in,
                              void* d_out, int out_size, void* d_ws, size_t ws_size,
                              hipStream_t stream) {
  const float* x  = (const float*)d_in[0];
  const float* Wb = (const float*)d_in[1];
  const float* bb = (const float*)d_in[2];
  const float* Wc = (const float*)d_in[3];
  const float* bc = (const float*)d_in[4];
  const float* Wd = (const float*)d_in[5];
  const float* bd = (const float*)d_in[6];
  char* ws = (char*)d_ws;
  ushort* xT   = (ushort*)(ws + WS_XT);
  ushort* dmat = (ushort*)(ws + WS_D);
  ushort* bT   = (ushort*)(ws + WS_BT);
  ushort* cT   = (ushort*)(ws + WS_CT);
  ushort* Wcat = (ushort*)(ws + WS_WCAT);
  float*  bcat = (float*)(ws + WS_BCAT);
  ushort* E    = (ushort*)(ws + WS_E);
  float*  out  = (float*)d_out;

  k_prep_w<<<1280, 256, 0, stream>>>(Wb, bb, Wc, bc, Wd, bd, Wcat, bcat);
  k_prep_xt<<<2048, 256, 0, stream>>>(x, xT);
  k_proj<<<640, 256, 0, stream>>>(Wcat, bcat, xT, bT, cT, dmat);
  if (ws_size >= WS_E_NEED) {
    k_stats_e<<<256, 512, 0, stream>>>(bT, cT, dmat, E);
    k_attn_e<<<512, 512, 0, stream>>>(dmat, E, x, out);
  } else {
    k_stats_f<<<256, 512, 0, stream>>>(bT, cT, dmat);
    k_attn_f<<<512, 512, 0, stream>>>(bT, cT, dmat, x, out);
  }
}